// Round 9
// baseline (511.500 us; speedup 1.0000x reference)
//
#include <hip/hip_runtime.h>
#include <cstdint>

#define N_ANCH 8400
#define WMAX   132          // ceil(8400/64)
#define NB     (WMAX * 64)  // padded box slots: 8448
#define NT     256          // k_scan threads: wave0 scans, all 4 waves emit
#define CSLOT  24           // register prefetch slots per block (double-buffered)

__device__ __forceinline__ uint64_t readlane64(uint64_t v, int lane) {
  unsigned lo = (unsigned)__builtin_amdgcn_readlane((int)(unsigned)(v & 0xffffffffull), lane);
  unsigned hi = (unsigned)__builtin_amdgcn_readlane((int)(unsigned)(v >> 32), lane);
  return ((uint64_t)hi << 32) | lo;
}
__device__ __forceinline__ uint64_t firstlane64(uint64_t v) {
  unsigned lo = (unsigned)__builtin_amdgcn_readfirstlane((int)(unsigned)(v & 0xffffffffull));
  unsigned hi = (unsigned)__builtin_amdgcn_readfirstlane((int)(unsigned)(v >> 32));
  return ((uint64_t)hi << 32) | lo;
}
__device__ __forceinline__ uint64_t shflxor64(uint64_t v, int m) {
  int lo = __shfl_xor((int)(unsigned)(v & 0xffffffffull), m, 64);
  int hi = __shfl_xor((int)(unsigned)(v >> 32), m, 64);
  return ((uint64_t)(unsigned)hi << 32) | (unsigned)lo;
}

// Kernel A: exact stable rank (descending score, invalid -> -inf, ties by index),
// scatter boxes/scores into sorted order, count valid. (verified)
__global__ __launch_bounds__(256) void k_rank(const float* __restrict__ in,
                                              float* __restrict__ scores_s,
                                              float4* __restrict__ boxes_s,
                                              unsigned* __restrict__ nvp) {
  __shared__ alignas(16) float sc[N_ANCH];
  __shared__ int part[256];
  const int tid = threadIdx.x;
  const float* srow = in + 4 * N_ANCH;
  for (int j = tid; j < N_ANCH; j += 256) sc[j] = srow[j];
  __syncthreads();
  const int il = tid & 63, q = tid >> 6;
  const int i = blockIdx.x * 64 + il;
  const float si = (i < N_ANCH) ? sc[i] : 0.0f;
  const bool valid = si > 0.5f;
  const float key = valid ? si : -INFINITY;
  int cnt = 0;
  const float4* sc4 = (const float4*)sc;
  const int jb = q * (N_ANCH / 4);
  for (int jj = 0; jj < (N_ANCH / 16); ++jj) {
    float4 v = sc4[q * (N_ANCH / 16) + jj];
    int j0 = jb + jj * 4;
    float k0 = (v.x > 0.5f) ? v.x : -INFINITY;
    float k1 = (v.y > 0.5f) ? v.y : -INFINITY;
    float k2 = (v.z > 0.5f) ? v.z : -INFINITY;
    float k3 = (v.w > 0.5f) ? v.w : -INFINITY;
    cnt += (k0 > key) || (k0 == key && (j0 + 0) < i);
    cnt += (k1 > key) || (k1 == key && (j0 + 1) < i);
    cnt += (k2 > key) || (k2 == key && (j0 + 2) < i);
    cnt += (k3 > key) || (k3 == key && (j0 + 3) < i);
  }
  part[tid] = cnt;
  __syncthreads();
  if (q == 0 && i < N_ANCH) {
    int r = part[il] + part[64 + il] + part[128 + il] + part[192 + il];
    float cx = in[0 * N_ANCH + i], cy = in[1 * N_ANCH + i];
    float w  = in[2 * N_ANCH + i], h  = in[3 * N_ANCH + i];
    float x1 = cx - w * 0.5f, y1 = cy - h * 0.5f;
    float x2 = cx + w * 0.5f, y2 = cy + h * 0.5f;
    boxes_s[r] = make_float4(x1, y1, x2, y2);
    scores_s[r] = valid ? si : 0.0f;
    if (valid) atomicAdd(nvp, 1u);
  }
}

// Kernel B: sup matrix, row-major stride Wp, UPPER TRIANGLE ONLY (w >= rowblock;
// the scan never reads w < rowblock), plus contiguous diag[]. Exact IoU path.
__global__ __launch_bounds__(256) void k_sup(const float4* __restrict__ boxes_s,
                                             const unsigned* __restrict__ nvp,
                                             unsigned long long* __restrict__ sup,
                                             unsigned long long* __restrict__ diag) {
  const int nv = (int)*nvp;
  const int W = (nv + 63) >> 6;
  const int Wp = (W + 1) & ~1;
  const int w = blockIdx.x;
  if (w >= W) return;
  if (w + 1 < (int)(blockIdx.y * 256) >> 6) return;   // whole block in lower triangle
  __shared__ float bx1[64], by1[64], bx2[64], by2[64], bar[64];
  const int tid = threadIdx.x;
  if (tid < 64) {
    int j = w * 64 + tid;
    float4 b = (j < N_ANCH) ? boxes_s[j] : make_float4(0.f, 0.f, 0.f, 0.f);
    bx1[tid] = b.x; by1[tid] = b.y; bx2[tid] = b.z; by2[tid] = b.w;
    bar[tid] = (b.z - b.x) * (b.w - b.y);
  }
  __syncthreads();
  const int i = blockIdx.y * 256 + tid;
  if (i >= nv) return;
  if (w < (i >> 6)) return;                            // lower triangle: never read
  float4 bi = boxes_s[i];
  float ai = (bi.z - bi.x) * (bi.w - bi.y);
  const int jmax = nv - w * 64;
  uint64_t bits = 0;
  #pragma unroll 8
  for (int l = 0; l < 64; ++l) {
    float lx = fmaxf(bi.x, bx1[l]);
    float ly = fmaxf(bi.y, by1[l]);
    float rx = fminf(bi.z, bx2[l]);
    float ry = fminf(bi.w, by2[l]);
    float dx = fmaxf(rx - lx, 0.0f);
    float dy = fmaxf(ry - ly, 0.0f);
    float inter = dx * dy;
    asm volatile("" : "+v"(inter));           // block fma-contraction into union
    float uni = (ai + bar[l]) - inter;        // reference op order
    float iou = inter / uni;                  // IEEE f32 div, matches numpy
    bits |= ((uint64_t)((l < jmax) && (iou > 0.5f))) << l;
  }
  sup[(size_t)i * Wp + w] = bits;
  if (w == (i >> 6)) diag[i] = bits;
}

// Kernel C: single-wave scan, zero barriers, DOUBLE-BUFFERED register prefetch
// issued ONE FULL STEP EARLY from the monotone-superset keep word, with
// wave-uniform SGPR row bases (ample VGPR budget via launch_bounds(256,1)).
__global__ __launch_bounds__(NT, 1) void k_scan(const float* __restrict__ scores_s,
                                                const float4* __restrict__ boxes_s,
                                                const unsigned long long* __restrict__ sup_,
                                                const unsigned long long* __restrict__ diag_g,
                                                const unsigned* __restrict__ nvp,
                                                float* __restrict__ out) {
  __shared__ uint64_t keep_s[WMAX];
  const uint64_t* sup = (const uint64_t*)sup_;
  const uint64_t* diag64 = (const uint64_t*)diag_g;
  const int tid = threadIdx.x;
  const int lane = tid & 63;
  const int wave = tid >> 6;
  const int nv = (int)*nvp;
  const int W  = (nv + 63) >> 6;
  const int Wp = (W + 1) & ~1;

  for (int idx = tid; idx < WMAX; idx += NT) {
    uint64_t v = 0; int base = idx * 64;
    if (base < nv) { int rem = nv - base; v = (rem >= 64) ? ~0ull : ((1ull << rem) - 1ull); }
    keep_s[idx] = v;
  }
  __syncthreads();

  if (wave == 0 && W > 0) {
    uint64_t preA[CSLOT], preB[CSLOT];
    uint64_t dwA = 0, dwB = 0;

    // Issue prefetch for block kk from the CURRENT (stale-superset) keep word.
    // Returns that word; loads use SGPR row bases + clamped per-lane offset.
    auto issueFor = [&](int kk, uint64_t (&pre)[CSLOT], uint64_t& dwn) -> uint64_t {
      if (kk >= W) {
        #pragma unroll
        for (int s = 0; s < CSLOT; ++s) pre[s] = 0;
        return 0;
      }
      uint64_t cw = firstlane64(keep_s[kk]);   // superset of final kept set
      dwn = diag64[(size_t)kk * 64 + lane];
      const int wdn = kk + 1 + lane;
      const bool inW = (wdn < W);
      const int wdc = inW ? wdn : 0;           // clamp: no OOB address
      uint64_t remc = cw;
      #pragma unroll
      for (int s = 0; s < CSLOT; ++s) {
        int r = remc ? (int)__builtin_ctzll(remc) : 0;
        bool v = (remc != 0);
        remc &= remc - 1;
        const uint64_t* base = sup + ((size_t)kk * 64 + r) * Wp;  // scalar base
        uint64_t val = v ? base[wdc] : 0ull;
        pre[s] = (v && inW) ? val : 0ull;
      }
      return cw;
    };

    // Resolve + apply block k using prefetched data.
    auto useStep = [&](int k, uint64_t (&pre)[CSLOT], uint64_t dwv, uint64_t cw) {
      uint64_t kw = firstlane64(keep_s[k]);    // fresh (post all prior applies)
      uint64_t bk = kw, cand = kw;
      while (cand) {
        int r = (int)__builtin_ctzll(cand);
        uint64_t sr = readlane64(dwv, r);
        uint64_t m = sr & ~((2ull << r) - 1ull);   // cols strictly > r
        cand &= ~(1ull << r);
        cand &= ~m;
        bk   &= ~m;
      }
      if (lane == 0) keep_s[k] = bk;

      const int wd = k + 1 + lane;
      uint64_t acc = 0;
      uint64_t remc = cw;
      #pragma unroll
      for (int s = 0; s < CSLOT; ++s) {
        int r = remc ? (int)__builtin_ctzll(remc) : 0;
        uint64_t mk = (uint64_t)0 - (uint64_t)((remc != 0) && ((bk >> r) & 1ull));
        remc &= remc - 1;
        acc |= pre[s] & mk;
      }
      // overflow: kept candidates beyond CSLOT (early blocks only), 8-batched
      uint64_t remo = remc & bk;
      const size_t rowbase = (size_t)k * 64;
      while (remo) {
        int r0 = (int)__builtin_ctzll(remo); remo &= remo - 1;
        uint64_t m1 = (uint64_t)0 - (uint64_t)(remo != 0);
        int r1 = remo ? (int)__builtin_ctzll(remo) : r0; remo &= remo - 1;
        uint64_t m2 = (uint64_t)0 - (uint64_t)(remo != 0);
        int r2 = remo ? (int)__builtin_ctzll(remo) : r0; remo &= remo - 1;
        uint64_t m3 = (uint64_t)0 - (uint64_t)(remo != 0);
        int r3 = remo ? (int)__builtin_ctzll(remo) : r0; remo &= remo - 1;
        uint64_t m4 = (uint64_t)0 - (uint64_t)(remo != 0);
        int r4 = remo ? (int)__builtin_ctzll(remo) : r0; remo &= remo - 1;
        uint64_t m5 = (uint64_t)0 - (uint64_t)(remo != 0);
        int r5 = remo ? (int)__builtin_ctzll(remo) : r0; remo &= remo - 1;
        uint64_t m6 = (uint64_t)0 - (uint64_t)(remo != 0);
        int r6 = remo ? (int)__builtin_ctzll(remo) : r0; remo &= remo - 1;
        uint64_t m7 = (uint64_t)0 - (uint64_t)(remo != 0);
        int r7 = remo ? (int)__builtin_ctzll(remo) : r0; remo &= remo - 1;
        if (wd < W) {
          uint64_t v0 = sup[(rowbase + r0) * Wp + wd];
          uint64_t v1 = sup[(rowbase + r1) * Wp + wd];
          uint64_t v2 = sup[(rowbase + r2) * Wp + wd];
          uint64_t v3 = sup[(rowbase + r3) * Wp + wd];
          uint64_t v4 = sup[(rowbase + r4) * Wp + wd];
          uint64_t v5 = sup[(rowbase + r5) * Wp + wd];
          uint64_t v6 = sup[(rowbase + r6) * Wp + wd];
          uint64_t v7 = sup[(rowbase + r7) * Wp + wd];
          acc |= v0 | (v1 & m1) | (v2 & m2) | (v3 & m3)
                    | (v4 & m4) | (v5 & m5) | (v6 & m6) | (v7 & m7);
        }
      }
      if (wd < W) keep_s[wd] &= ~acc;

      // tail words beyond 64-lane coverage (first iterations only)
      for (int wd2 = k + 65; wd2 < W; ++wd2) {
        uint64_t v = 0;
        if ((bk >> lane) & 1ull) v = sup[(rowbase + lane) * Wp + wd2];
        v |= shflxor64(v, 1);  v |= shflxor64(v, 2);  v |= shflxor64(v, 4);
        v |= shflxor64(v, 8);  v |= shflxor64(v, 16); v |= shflxor64(v, 32);
        if (lane == 0) keep_s[wd2] &= ~v;
      }
    };

    uint64_t cwA = issueFor(0, preA, dwA);
    uint64_t cwB;
    for (int k = 0; k < W; k += 2) {
      cwB = issueFor(k + 1, preB, dwB);   // issued BEFORE apply-k: superset ok
      useStep(k, preA, dwA, cwA);
      cwA = issueFor(k + 2, preA, dwA);   // preA free again; one step of distance
      if (k + 1 < W) useStep(k + 1, preB, dwB, cwB);
    }
  }
  __syncthreads();

  // ---- emit output (all 4 waves) ----
  for (int r = tid; r < N_ANCH; r += NT) {
    bool kept = (r < nv) && ((keep_s[r >> 6] >> (r & 63)) & 1ull);
    float4 b = kept ? boxes_s[r] : make_float4(0.f, 0.f, 0.f, 0.f);
    float s = kept ? scores_s[r] : 0.0f;
    out[r * 5 + 0] = b.x;
    out[r * 5 + 1] = b.y;
    out[r * 5 + 2] = b.z;
    out[r * 5 + 3] = b.w;
    out[r * 5 + 4] = s;
  }
}

extern "C" void kernel_launch(void* const* d_in, const int* in_sizes, int n_in,
                              void* d_out, int out_size, void* d_ws, size_t ws_size,
                              hipStream_t stream) {
  const float* in = (const float*)d_in[0];
  float* out = (float*)d_out;
  uint8_t* ws = (uint8_t*)d_ws;
  unsigned* nvp = (unsigned*)ws;                                       // 64 B
  float* scores_s = (float*)(ws + 64);                                 // 33600 B
  float4* boxes_s = (float4*)(ws + 64 + 33600);                        // NB*16 = 135168 B
  unsigned long long* diag = (unsigned long long*)(ws + 64 + 33600 + (size_t)NB * 16);   // NB*8
  unsigned long long* sup  = (unsigned long long*)(ws + 64 + 33600 + (size_t)NB * 24);   // ~2.3 MB

  (void)hipMemsetAsync(ws, 0, 64, stream);
  k_rank<<<dim3(WMAX), dim3(256), 0, stream>>>(in, scores_s, boxes_s, nvp);
  k_sup<<<dim3(WMAX, (N_ANCH + 255) / 256), dim3(256), 0, stream>>>(boxes_s, nvp, sup, diag);
  k_scan<<<dim3(1), dim3(NT), 0, stream>>>(scores_s, boxes_s, sup, diag, nvp, out);
}

// Round 10
// 287.343 us; speedup vs baseline: 1.7801x; 1.7801x over previous
//
#include <hip/hip_runtime.h>
#include <cstdint>

#define N_ANCH 8400
#define WMAX   132          // ceil(8400/64)
#define NB     (WMAX * 64)  // padded box slots: 8448
#define NT     256          // k_scan threads (4 waves); covers W-4 <= 128 apply words

__device__ __forceinline__ uint64_t readlane64(uint64_t v, int lane) {
  unsigned lo = (unsigned)__builtin_amdgcn_readlane((int)(unsigned)(v & 0xffffffffull), lane);
  unsigned hi = (unsigned)__builtin_amdgcn_readlane((int)(unsigned)(v >> 32), lane);
  return ((uint64_t)hi << 32) | lo;
}

// Kernel A: exact stable rank (descending score, invalid -> -inf, ties by index),
// scatter boxes/scores into sorted order, count valid. (verified)
__global__ __launch_bounds__(256) void k_rank(const float* __restrict__ in,
                                              float* __restrict__ scores_s,
                                              float4* __restrict__ boxes_s,
                                              unsigned* __restrict__ nvp) {
  __shared__ alignas(16) float sc[N_ANCH];
  __shared__ int part[256];
  const int tid = threadIdx.x;
  const float* srow = in + 4 * N_ANCH;
  for (int j = tid; j < N_ANCH; j += 256) sc[j] = srow[j];
  __syncthreads();
  const int il = tid & 63, q = tid >> 6;
  const int i = blockIdx.x * 64 + il;
  const float si = (i < N_ANCH) ? sc[i] : 0.0f;
  const bool valid = si > 0.5f;
  const float key = valid ? si : -INFINITY;
  int cnt = 0;
  const float4* sc4 = (const float4*)sc;
  const int jb = q * (N_ANCH / 4);
  for (int jj = 0; jj < (N_ANCH / 16); ++jj) {
    float4 v = sc4[q * (N_ANCH / 16) + jj];
    int j0 = jb + jj * 4;
    float k0 = (v.x > 0.5f) ? v.x : -INFINITY;
    float k1 = (v.y > 0.5f) ? v.y : -INFINITY;
    float k2 = (v.z > 0.5f) ? v.z : -INFINITY;
    float k3 = (v.w > 0.5f) ? v.w : -INFINITY;
    cnt += (k0 > key) || (k0 == key && (j0 + 0) < i);
    cnt += (k1 > key) || (k1 == key && (j0 + 1) < i);
    cnt += (k2 > key) || (k2 == key && (j0 + 2) < i);
    cnt += (k3 > key) || (k3 == key && (j0 + 3) < i);
  }
  part[tid] = cnt;
  __syncthreads();
  if (q == 0 && i < N_ANCH) {
    int r = part[il] + part[64 + il] + part[128 + il] + part[192 + il];
    float cx = in[0 * N_ANCH + i], cy = in[1 * N_ANCH + i];
    float w  = in[2 * N_ANCH + i], h  = in[3 * N_ANCH + i];
    float x1 = cx - w * 0.5f, y1 = cy - h * 0.5f;
    float x2 = cx + w * 0.5f, y2 = cy + h * 0.5f;
    boxes_s[r] = make_float4(x1, y1, x2, y2);
    scores_s[r] = valid ? si : 0.0f;
    if (valid) atomicAdd(nvp, 1u);
  }
}

// Kernel B: sup matrix, row-major, stride Wp = (W+3)&~3 (32B-aligned 4-word
// groups), UPPER TRIANGLE ONLY (w >= rowblock). Exact verified IoU path.
__global__ __launch_bounds__(256) void k_sup(const float4* __restrict__ boxes_s,
                                             const unsigned* __restrict__ nvp,
                                             unsigned long long* __restrict__ sup) {
  const int nv = (int)*nvp;
  const int W = (nv + 63) >> 6;
  const int Wp = (W + 3) & ~3;
  const int w = blockIdx.x;
  if (w >= W) return;
  if (w + 1 < (int)(blockIdx.y * 256) >> 6) return;   // whole block in lower triangle
  __shared__ float bx1[64], by1[64], bx2[64], by2[64], bar[64];
  const int tid = threadIdx.x;
  if (tid < 64) {
    int j = w * 64 + tid;
    float4 b = (j < N_ANCH) ? boxes_s[j] : make_float4(0.f, 0.f, 0.f, 0.f);
    bx1[tid] = b.x; by1[tid] = b.y; bx2[tid] = b.z; by2[tid] = b.w;
    bar[tid] = (b.z - b.x) * (b.w - b.y);
  }
  __syncthreads();
  const int i = blockIdx.y * 256 + tid;
  if (i >= nv) return;
  if (w < (i >> 6)) return;                            // lower triangle: never read
  float4 bi = boxes_s[i];
  float ai = (bi.z - bi.x) * (bi.w - bi.y);
  const int jmax = nv - w * 64;
  uint64_t bits = 0;
  #pragma unroll 8
  for (int l = 0; l < 64; ++l) {
    float lx = fmaxf(bi.x, bx1[l]);
    float ly = fmaxf(bi.y, by1[l]);
    float rx = fminf(bi.z, bx2[l]);
    float ry = fminf(bi.w, by2[l]);
    float dx = fmaxf(rx - lx, 0.0f);
    float dy = fmaxf(ry - ly, 0.0f);
    float inter = dx * dy;
    asm volatile("" : "+v"(inter));           // block fma-contraction into union
    float uni = (ai + bar[l]) - inter;        // reference op order
    float iou = inter / uni;                  // IEEE f32 div, matches numpy
    bits |= ((uint64_t)((l < jmax) && (iou > 0.5f))) << l;
  }
  sup[(size_t)i * Wp + w] = bits;
}

// ---- k_scan macros: G=4 grouped scan, named-register double-buffered diag ----
// Buffer P holds, for lane l, rows {l,64+l,128+l,192+l} of group gg:
//   P i j = word (4gg+j) of row (256gg + 64i + l), only j >= i kept.
#define ISSUE(P, gg)                                                           \
  do {                                                                         \
    if ((gg) < NG) {                                                           \
      const size_t rb_ = (size_t)(gg) * 256 + (size_t)lane;                    \
      const size_t o_  = (size_t)(gg) * 4;                                     \
      { ulonglong2 t = *(const ulonglong2*)(sup + rb_ * Wp + o_);              \
        P##00 = t.x; P##01 = t.y; }                                            \
      { ulonglong2 t = *(const ulonglong2*)(sup + rb_ * Wp + o_ + 2);          \
        P##02 = t.x; P##03 = t.y; }                                            \
      { ulonglong2 t = *(const ulonglong2*)(sup + (rb_ + 64) * Wp + o_);       \
        P##11 = t.y; }                                                         \
      { ulonglong2 t = *(const ulonglong2*)(sup + (rb_ + 64) * Wp + o_ + 2);   \
        P##12 = t.x; P##13 = t.y; }                                            \
      { ulonglong2 t = *(const ulonglong2*)(sup + (rb_ + 128) * Wp + o_ + 2);  \
        P##22 = t.x; P##23 = t.y; }                                            \
      { ulonglong2 t = *(const ulonglong2*)(sup + (rb_ + 192) * Wp + o_ + 2);  \
        P##33 = t.y; }                                                         \
    } else {                                                                   \
      P##00 = P##01 = P##02 = P##03 = 0; P##11 = P##12 = P##13 = 0;            \
      P##22 = P##23 = 0; P##33 = 0;                                            \
    }                                                                          \
  } while (0)

#define RESOLVE(P, g4)                                                         \
  do {                                                                         \
    uint64_t kw0 = keep_s[(g4) + 0], kw1 = keep_s[(g4) + 1];                   \
    uint64_t kw2 = keep_s[(g4) + 2], kw3 = keep_s[(g4) + 3];                   \
    uint64_t cand;                                                             \
    cand = kw0;                                                                \
    while (cand) { int r = (int)__builtin_ctzll(cand);                         \
      uint64_t m0 = readlane64(P##00, r) & ~((2ull << r) - 1ull);              \
      cand &= ~(1ull << r); cand &= ~m0; kw0 &= ~m0;                           \
      kw1 &= ~readlane64(P##01, r);                                            \
      kw2 &= ~readlane64(P##02, r);                                            \
      kw3 &= ~readlane64(P##03, r); }                                          \
    cand = kw1;                                                                \
    while (cand) { int r = (int)__builtin_ctzll(cand);                         \
      uint64_t m1 = readlane64(P##11, r) & ~((2ull << r) - 1ull);              \
      cand &= ~(1ull << r); cand &= ~m1; kw1 &= ~m1;                           \
      kw2 &= ~readlane64(P##12, r);                                            \
      kw3 &= ~readlane64(P##13, r); }                                          \
    cand = kw2;                                                                \
    while (cand) { int r = (int)__builtin_ctzll(cand);                         \
      uint64_t m2 = readlane64(P##22, r) & ~((2ull << r) - 1ull);              \
      cand &= ~(1ull << r); cand &= ~m2; kw2 &= ~m2;                           \
      kw3 &= ~readlane64(P##23, r); }                                          \
    cand = kw3;                                                                \
    while (cand) { int r = (int)__builtin_ctzll(cand);                         \
      uint64_t m3 = readlane64(P##33, r) & ~((2ull << r) - 1ull);              \
      cand &= ~(1ull << r); cand &= ~m3; kw3 &= ~m3; }                         \
    if (lane == 0) { keep_s[(g4) + 0] = kw0; keep_s[(g4) + 1] = kw1;           \
                     keep_s[(g4) + 2] = kw2; keep_s[(g4) + 3] = kw3; }         \
  } while (0)

#define NEXTROW(rv)                                                            \
  int rv;                                                                      \
  { while (rem == 0 && jw < 3) { ++jw; rem = (jw == 1) ? w1 : ((jw == 2) ? w2 : w3); } \
    if (rem) { rv = (int)__builtin_ctzll(rem) + (jw << 6); rem &= rem - 1; }   \
    else rv = -1; }

#define APPLY(g4)                                                              \
  do {                                                                         \
    const int wd = (g4) + 4 + tid;                                             \
    const bool act = (wd < W);                                                 \
    uint64_t w1 = keep_s[(g4) + 1], w2 = keep_s[(g4) + 2], w3 = keep_s[(g4) + 3]; \
    const size_t gb = (size_t)(g4) * 64;                                       \
    int jw = 0; uint64_t rem = keep_s[(g4) + 0];                               \
    uint64_t acc = 0;                                                          \
    for (;;) {                                                                 \
      NEXTROW(r0); if (r0 < 0) break;                                          \
      NEXTROW(r1); uint64_t m1 = (uint64_t)0 - (uint64_t)(r1 >= 0); if (r1 < 0) r1 = r0; \
      NEXTROW(r2); uint64_t m2 = (uint64_t)0 - (uint64_t)(r2 >= 0); if (r2 < 0) r2 = r0; \
      NEXTROW(r3); uint64_t m3 = (uint64_t)0 - (uint64_t)(r3 >= 0); if (r3 < 0) r3 = r0; \
      NEXTROW(r4); uint64_t m4 = (uint64_t)0 - (uint64_t)(r4 >= 0); if (r4 < 0) r4 = r0; \
      NEXTROW(r5); uint64_t m5 = (uint64_t)0 - (uint64_t)(r5 >= 0); if (r5 < 0) r5 = r0; \
      NEXTROW(r6); uint64_t m6 = (uint64_t)0 - (uint64_t)(r6 >= 0); if (r6 < 0) r6 = r0; \
      NEXTROW(r7); uint64_t m7 = (uint64_t)0 - (uint64_t)(r7 >= 0); if (r7 < 0) r7 = r0; \
      if (act) {                                                               \
        uint64_t v0 = sup[(gb + r0) * Wp + wd];                                \
        uint64_t v1 = sup[(gb + r1) * Wp + wd];                                \
        uint64_t v2 = sup[(gb + r2) * Wp + wd];                                \
        uint64_t v3 = sup[(gb + r3) * Wp + wd];                                \
        uint64_t v4 = sup[(gb + r4) * Wp + wd];                                \
        uint64_t v5 = sup[(gb + r5) * Wp + wd];                                \
        uint64_t v6 = sup[(gb + r6) * Wp + wd];                                \
        uint64_t v7 = sup[(gb + r7) * Wp + wd];                                \
        acc |= v0 | (v1 & m1) | (v2 & m2) | (v3 & m3)                          \
                  | (v4 & m4) | (v5 & m5) | (v6 & m6) | (v7 & m7);             \
      }                                                                        \
    }                                                                          \
    if (act) keep_s[wd] &= ~acc;                                               \
  } while (0)

// raw barrier: LDS-ordered, does NOT drain vmcnt (prefetch stays in flight)
#define BARRIER()                                                              \
  do { asm volatile("s_waitcnt lgkmcnt(0)" ::: "memory");                      \
       __builtin_amdgcn_sched_barrier(0);                                      \
       __builtin_amdgcn_s_barrier();                                           \
       __builtin_amdgcn_sched_barrier(0); } while (0)

#define STEP(P, Q, g)                                                          \
  do {                                                                         \
    if ((g) < NG) {                                                            \
      const int g4_ = (g) * 4;                                                 \
      if (wave == 0) { ISSUE(Q, (g) + 1); RESOLVE(P, g4_); }                   \
      BARRIER();                                                               \
      APPLY(g4_);                                                              \
      BARRIER();                                                               \
    }                                                                          \
  } while (0)

// Kernel C: grouped (G=4) single-workgroup scan. Wave0 resolves 256-row
// diagonal band from named registers (double-buffered, prefetched 1 superstep
// ahead — group-diag is keep-independent, so prefetch is always valid);
// all waves apply kept rows to words g4+4..W-1 in 8-batched coalesced loads.
__global__ __launch_bounds__(NT, 1) void k_scan(const float* __restrict__ scores_s,
                                                const float4* __restrict__ boxes_s,
                                                const unsigned long long* __restrict__ sup_,
                                                const unsigned* __restrict__ nvp,
                                                float* __restrict__ out) {
  __shared__ uint64_t keep_s[WMAX + 4];
  const uint64_t* sup = (const uint64_t*)sup_;
  const int tid = threadIdx.x;
  const int lane = tid & 63;
  const int wave = tid >> 6;
  const int nv = (int)*nvp;
  const int W  = (nv + 63) >> 6;
  const int Wp = (W + 3) & ~3;
  const int NG = (W + 3) >> 2;

  for (int idx = tid; idx < WMAX + 4; idx += NT) {
    uint64_t v = 0; int base = idx * 64;
    if (base < nv) { int rem2 = nv - base; v = (rem2 >= 64) ? ~0ull : ((1ull << rem2) - 1ull); }
    keep_s[idx] = v;
  }
  __syncthreads();

  if (W > 0) {
    uint64_t A00, A01, A02, A03, A11, A12, A13, A22, A23, A33;
    uint64_t B00, B01, B02, B03, B11, B12, B13, B22, B23, B33;
    if (wave == 0) ISSUE(A, 0);
    for (int g = 0; g < NG; g += 2) {
      STEP(A, B, g);
      STEP(B, A, g + 1);
    }
  }
  __syncthreads();

  // ---- emit output (all waves) ----
  for (int r = tid; r < N_ANCH; r += NT) {
    bool kept = (r < nv) && ((keep_s[r >> 6] >> (r & 63)) & 1ull);
    float4 b = kept ? boxes_s[r] : make_float4(0.f, 0.f, 0.f, 0.f);
    float s = kept ? scores_s[r] : 0.0f;
    out[r * 5 + 0] = b.x;
    out[r * 5 + 1] = b.y;
    out[r * 5 + 2] = b.z;
    out[r * 5 + 3] = b.w;
    out[r * 5 + 4] = s;
  }
}

extern "C" void kernel_launch(void* const* d_in, const int* in_sizes, int n_in,
                              void* d_out, int out_size, void* d_ws, size_t ws_size,
                              hipStream_t stream) {
  const float* in = (const float*)d_in[0];
  float* out = (float*)d_out;
  uint8_t* ws = (uint8_t*)d_ws;
  unsigned* nvp = (unsigned*)ws;                                       // 64 B
  float* scores_s = (float*)(ws + 64);                                 // 33600 B
  float4* boxes_s = (float4*)(ws + 64 + 33600);                        // NB*16 = 135168 B
  unsigned long long* sup = (unsigned long long*)(ws + 64 + 33600 + (size_t)NB * 16);  // NB*Wp*8

  (void)hipMemsetAsync(ws, 0, 64, stream);
  k_rank<<<dim3(WMAX), dim3(256), 0, stream>>>(in, scores_s, boxes_s, nvp);
  k_sup<<<dim3(WMAX, (N_ANCH + 255) / 256), dim3(256), 0, stream>>>(boxes_s, nvp, sup);
  k_scan<<<dim3(1), dim3(NT), 0, stream>>>(scores_s, boxes_s, sup, nvp, out);
}